// Round 1
// baseline (220.092 us; speedup 1.0000x reference)
//
#include <hip/hip_runtime.h>

typedef unsigned short u16;
typedef __attribute__((ext_vector_type(8))) short short8;
typedef __attribute__((ext_vector_type(4))) short short4v;
typedef __attribute__((ext_vector_type(4))) float f32x4;

__device__ __forceinline__ u16 f2bf(float f) {
  union { float f; unsigned u; } a; a.f = f;
  unsigned u = a.u + 0x7fffu + ((a.u >> 16) & 1u);
  return (u16)(u >> 16);
}

// ---------------- x: f32 -> bf16 ----------------
__global__ void cvt_x_kernel(const float* __restrict__ x, u16* __restrict__ xb) {
  int i = (blockIdx.x * 256 + threadIdx.x) * 8;
  float4 a = *(const float4*)(x + i);
  float4 b = *(const float4*)(x + i + 4);
  short8 v;
  v[0] = (short)f2bf(a.x); v[1] = (short)f2bf(a.y);
  v[2] = (short)f2bf(a.z); v[3] = (short)f2bf(a.w);
  v[4] = (short)f2bf(b.x); v[5] = (short)f2bf(b.y);
  v[6] = (short)f2bf(b.z); v[7] = (short)f2bf(b.w);
  *(short8*)(xb + i) = v;
}

// ---------------- weight prep: transpose to N-major bf16; fold quadrant mix into Wk ----------------
// z=0: Wq -> Wcat rows [0,1024);  z=1: Wk_eff -> rows [1024,2048);  z=2: Wv -> rows [2048,3072); z=3: Wo -> Wot
__global__ void prep_w_kernel(const float* __restrict__ Wq, const float* __restrict__ Wk,
                              const float* __restrict__ Wv, const float* __restrict__ Wo,
                              const float* __restrict__ qw,
                              u16* __restrict__ Wcat, u16* __restrict__ Wot) {
  __shared__ float tile[32][33];
  const int z = blockIdx.z;
  const int n0 = blockIdx.x * 32, k0 = blockIdx.y * 32;
  const float* src = (z == 0) ? Wq : (z == 1) ? Wk : (z == 2) ? Wv : Wo;
  float w0 = 0.f, w1 = 0.f, w2 = 0.f, w3 = 0.f;
  if (z == 1) {
    float a = qw[0], b = qw[1], c = qw[2], d = qw[3];
    float mx = fmaxf(fmaxf(a, b), fmaxf(c, d));
    float ea = expf(a - mx), eb = expf(b - mx), ec = expf(c - mx), ed = expf(d - mx);
    float s = ea + eb + ec + ed;
    w0 = ea / s; w1 = eb / s; w2 = ec / s; w3 = ed / s;
  }
  #pragma unroll
  for (int i = 0; i < 32; i += 8) {
    int k = k0 + threadIdx.y + i;
    int n = n0 + threadIdx.x;
    float v;
    if (z == 1) {
      int c = n & 63;
      if (c < 32) v = w0 * src[k * 1024 + n]      + w1 * src[k * 1024 + n + 32];
      else        v = w2 * src[k * 1024 + n - 32] + w3 * src[k * 1024 + n];
    } else {
      v = src[k * 1024 + n];
    }
    tile[threadIdx.y + i][threadIdx.x] = v;
  }
  __syncthreads();
  #pragma unroll
  for (int i = 0; i < 32; i += 8) {
    int n = n0 + threadIdx.y + i;
    int k = k0 + threadIdx.x;
    u16 v = f2bf(tile[threadIdx.x][threadIdx.y + i]);
    if (z < 3) Wcat[(size_t)(z * 1024 + n) * 1024 + k] = v;
    else       Wot[(size_t)n * 1024 + k] = v;
  }
}

// ---------------- GEMM: C[M,N] = A[M,K] * B^T[N,K]  (both row-major, k-contiguous) ----------------
// MODE 0: A=xb(4096x1024), B=Wcat(3072x1024): n<1024 -> Q, n<2048 -> K, else -> Vt (B,H,64,T) transposed store.
// MODE 1: A=Ob(4096x1024), B=Wot(1024x1024): f32 out to d_out.
template<int MODE>
__global__ __launch_bounds__(256, 2)
void gemm_k(const u16* __restrict__ A, const u16* __restrict__ Bm,
            u16* __restrict__ out_q, u16* __restrict__ out_k,
            u16* __restrict__ out_vt, float* __restrict__ out_f) {
  __shared__ u16 At[128 * 32];
  __shared__ u16 Bt[128 * 32];
  const int tid = threadIdx.x;
  const int wid = tid >> 6, lane = tid & 63;
  const int l15 = lane & 15, l4 = lane >> 4;
  const int mblk = blockIdx.y * 128, nblk = blockIdx.x * 128;
  const int wm = (wid >> 1) * 64, wn = (wid & 1) * 64;
  f32x4 acc[4][4] = {};

  // staging: each wave stages 32 rows (2 calls x 16 rows); lane -> row=lane>>2, 16B chunk=lane&3
  const int rA = wid * 32 + (lane >> 2);
  const int cA = (lane & 3) * 8;
  const u16* gA = A  + (size_t)(mblk + rA) * 1024 + cA;
  const u16* gB = Bm + (size_t)(nblk + rA) * 1024 + cA;

  for (int kt = 0; kt < 1024; kt += 32) {
    __syncthreads();
    #pragma unroll
    for (int q = 0; q < 2; ++q) {
      __builtin_amdgcn_global_load_lds(
          (__attribute__((address_space(1))) void*)(u16*)(gA + (size_t)q * 16 * 1024 + kt),
          (__attribute__((address_space(3))) void*)(At + (wid * 32 + q * 16) * 32),
          16, 0, 0);
      __builtin_amdgcn_global_load_lds(
          (__attribute__((address_space(1))) void*)(u16*)(gB + (size_t)q * 16 * 1024 + kt),
          (__attribute__((address_space(3))) void*)(Bt + (wid * 32 + q * 16) * 32),
          16, 0, 0);
    }
    __syncthreads();
    short8 af[4], bf[4];
    #pragma unroll
    for (int t = 0; t < 4; ++t) {
      af[t] = *(const short8*)(At + (wm + t * 16 + l15) * 32 + l4 * 8);
      bf[t] = *(const short8*)(Bt + (wn + t * 16 + l15) * 32 + l4 * 8);
    }
    #pragma unroll
    for (int i = 0; i < 4; ++i)
      #pragma unroll
      for (int j = 0; j < 4; ++j)
        acc[i][j] = __builtin_amdgcn_mfma_f32_16x16x32_bf16(af[i], bf[j], acc[i][j], 0, 0, 0);
  }

  // epilogue: D row m=(lane>>4)*4+j (+16*i), col n=lane&15 (+16*j-tile)
  #pragma unroll
  for (int i = 0; i < 4; ++i) {
    int m_g = mblk + wm + i * 16 + l4 * 4;
    #pragma unroll
    for (int j = 0; j < 4; ++j) {
      int n_g = nblk + wn + j * 16 + l15;
      f32x4 v = acc[i][j];
      if (MODE == 1) {
        #pragma unroll
        for (int jj = 0; jj < 4; ++jj)
          out_f[(size_t)(m_g + jj) * 1024 + n_g] = v[jj];
      } else {
        if (n_g < 2048) {
          u16* dst = (n_g < 1024) ? out_q : out_k;
          int nn = n_g & 1023;
          #pragma unroll
          for (int jj = 0; jj < 4; ++jj)
            dst[(size_t)(m_g + jj) * 1024 + nn] = f2bf(v[jj]);
        } else {
          int c = n_g - 2048;
          int b = m_g >> 11, t = m_g & 2047;
          short4v p;
          p[0] = (short)f2bf(v[0]); p[1] = (short)f2bf(v[1]);
          p[2] = (short)f2bf(v[2]); p[3] = (short)f2bf(v[3]);
          *(short4v*)(out_vt + ((size_t)((b << 4) + (c >> 6)) * 64 + (c & 63)) * 2048 + t) = p;
        }
      }
    }
  }
}

// ---------------- flash attention ----------------
// grid (T/128, B*H); 4 waves, each wave owns 32 q-rows. KBLK=64. K/V frags from global (L2-resident).
__global__ __launch_bounds__(256, 2)
void attn_k(const u16* __restrict__ Q, const u16* __restrict__ Kb,
            const u16* __restrict__ Vt, u16* __restrict__ O) {
  __shared__ u16 plds[4][32 * 64];
  const int tid = threadIdx.x, wid = tid >> 6, lane = tid & 63;
  const int l15 = lane & 15, l4 = lane >> 4;
  const int qt = blockIdx.x, bh = blockIdx.y;
  const int b = bh >> 4, h = bh & 15;
  const int qrow0 = qt * 128 + wid * 32;
  const float c1 = 0.17677669529663687f * 1.4426950408889634f;  // 32^-0.5 * log2(e)

  short8 aq[2][2];
  #pragma unroll
  for (int mt = 0; mt < 2; ++mt)
    #pragma unroll
    for (int kk = 0; kk < 2; ++kk)
      aq[mt][kk] = *(const short8*)(Q + (size_t)(b * 2048 + qrow0 + mt * 16 + l15) * 1024
                                      + h * 64 + kk * 32 + l4 * 8);

  const u16* Kp = Kb + (size_t)b * 2048 * 1024 + h * 64;
  const u16* Vp = Vt + (size_t)bh * 64 * 2048;
  u16* pw = (u16*)plds[wid];

  f32x4 accO[2][4] = {};
  float mrun[2][4], lrun[2][4];
  #pragma unroll
  for (int mt = 0; mt < 2; ++mt)
    #pragma unroll
    for (int jj = 0; jj < 4; ++jj) { mrun[mt][jj] = -1e30f; lrun[mt][jj] = 0.f; }

  for (int kt = 0; kt < 2048; kt += 64) {
    short8 kf[4][2];
    #pragma unroll
    for (int nt = 0; nt < 4; ++nt)
      #pragma unroll
      for (int kk = 0; kk < 2; ++kk)
        kf[nt][kk] = *(const short8*)(Kp + (size_t)(kt + nt * 16 + l15) * 1024 + kk * 32 + l4 * 8);

    f32x4 s[2][4] = {};
    #pragma unroll
    for (int mt = 0; mt < 2; ++mt)
      #pragma unroll
      for (int nt = 0; nt < 4; ++nt)
        #pragma unroll
        for (int kk = 0; kk < 2; ++kk)
          s[mt][nt] = __builtin_amdgcn_mfma_f32_16x16x32_bf16(aq[mt][kk], kf[nt][kk], s[mt][nt], 0, 0, 0);

    #pragma unroll
    for (int mt = 0; mt < 2; ++mt)
      #pragma unroll
      for (int nt = 0; nt < 4; ++nt)
        s[mt][nt] *= c1;

    float alpha[2][4];
    #pragma unroll
    for (int mt = 0; mt < 2; ++mt)
      #pragma unroll
      for (int jj = 0; jj < 4; ++jj) {
        float mx = fmaxf(fmaxf(s[mt][0][jj], s[mt][1][jj]), fmaxf(s[mt][2][jj], s[mt][3][jj]));
        mx = fmaxf(mx, __shfl_xor(mx, 1, 64));
        mx = fmaxf(mx, __shfl_xor(mx, 2, 64));
        mx = fmaxf(mx, __shfl_xor(mx, 4, 64));
        mx = fmaxf(mx, __shfl_xor(mx, 8, 64));
        float mnew = fmaxf(mrun[mt][jj], mx);
        float al = exp2f(mrun[mt][jj] - mnew);
        mrun[mt][jj] = mnew;
        alpha[mt][jj] = al;
        lrun[mt][jj] *= al;
      }

    #pragma unroll
    for (int mt = 0; mt < 2; ++mt)
      #pragma unroll
      for (int jj = 0; jj < 4; ++jj) {
        float m_ = mrun[mt][jj];
        float p0 = exp2f(s[mt][0][jj] - m_);
        float p1 = exp2f(s[mt][1][jj] - m_);
        float p2 = exp2f(s[mt][2][jj] - m_);
        float p3 = exp2f(s[mt][3][jj] - m_);
        s[mt][0][jj] = p0; s[mt][1][jj] = p1; s[mt][2][jj] = p2; s[mt][3][jj] = p3;
        float rs = (p0 + p1) + (p2 + p3);
        rs += __shfl_xor(rs, 1, 64);
        rs += __shfl_xor(rs, 2, 64);
        rs += __shfl_xor(rs, 4, 64);
        rs += __shfl_xor(rs, 8, 64);
        lrun[mt][jj] += rs;
      }

    #pragma unroll
    for (int mt = 0; mt < 2; ++mt)
      #pragma unroll
      for (int dn = 0; dn < 4; ++dn) {
        f32x4 a4 = accO[mt][dn];
        a4[0] *= alpha[mt][0]; a4[1] *= alpha[mt][1];
        a4[2] *= alpha[mt][2]; a4[3] *= alpha[mt][3];
        accO[mt][dn] = a4;
      }

    // P -> per-wave LDS (XOR-swizzled 16B chunks: phys_ch = ch ^ (row&7))
    #pragma unroll
    for (int mt = 0; mt < 2; ++mt)
      #pragma unroll
      for (int nt = 0; nt < 4; ++nt)
        #pragma unroll
        for (int jj = 0; jj < 4; ++jj) {
          int r = mt * 16 + l4 * 4 + jj;
          int col = nt * 16 + l15;
          int ch = col >> 3;
          pw[r * 64 + ((ch ^ (r & 7)) << 3) + (col & 7)] = f2bf(s[mt][nt][jj]);
        }

    short8 ap[2][2];
    #pragma unroll
    for (int mt = 0; mt < 2; ++mt)
      #pragma unroll
      for (int kc = 0; kc < 2; ++kc) {
        int r = mt * 16 + l15;
        int ch = kc * 4 + l4;
        ap[mt][kc] = *(const short8*)(pw + r * 64 + ((ch ^ (r & 7)) << 3));
      }

    short8 vf[4][2];
    #pragma unroll
    for (int dn = 0; dn < 4; ++dn)
      #pragma unroll
      for (int kc = 0; kc < 2; ++kc)
        vf[dn][kc] = *(const short8*)(Vp + (size_t)(dn * 16 + l15) * 2048 + kt + kc * 32 + l4 * 8);

    #pragma unroll
    for (int mt = 0; mt < 2; ++mt)
      #pragma unroll
      for (int dn = 0; dn < 4; ++dn)
        #pragma unroll
        for (int kc = 0; kc < 2; ++kc)
          accO[mt][dn] = __builtin_amdgcn_mfma_f32_16x16x32_bf16(ap[mt][kc], vf[dn][kc], accO[mt][dn], 0, 0, 0);
  }

  #pragma unroll
  for (int mt = 0; mt < 2; ++mt) {
    float inv[4];
    #pragma unroll
    for (int jj = 0; jj < 4; ++jj) inv[jj] = 1.0f / lrun[mt][jj];
    #pragma unroll
    for (int dn = 0; dn < 4; ++dn)
      #pragma unroll
      for (int jj = 0; jj < 4; ++jj) {
        int row = b * 2048 + qrow0 + mt * 16 + l4 * 4 + jj;
        int col = h * 64 + dn * 16 + l15;
        O[(size_t)row * 1024 + col] = f2bf(accO[mt][dn][jj] * inv[jj]);
      }
  }
}

// ---------------- launch ----------------
extern "C" void kernel_launch(void* const* d_in, const int* in_sizes, int n_in,
                              void* d_out, int out_size, void* d_ws, size_t ws_size,
                              hipStream_t stream) {
  const float* x  = (const float*)d_in[0];
  const float* Wq = (const float*)d_in[1];
  const float* Wk = (const float*)d_in[2];
  const float* Wv = (const float*)d_in[3];
  const float* Wo = (const float*)d_in[4];
  const float* qw = (const float*)d_in[5];

  char* w = (char*)d_ws;
  u16* xb   = (u16*)(w);                      // 8 MiB  (4096x1024 bf16)
  u16* Wcat = (u16*)(w + (8u  << 20));        // 6 MiB  (3072x1024 bf16, N-major)
  u16* Wot  = (u16*)(w + (14u << 20));        // 2 MiB  (1024x1024 bf16, N-major)
  u16* Qb   = (u16*)(w + (16u << 20));        // 8 MiB  (4096x1024)
  u16* Kb   = (u16*)(w + (24u << 20));        // 8 MiB  (4096x1024)
  u16* Vtb  = (u16*)(w + (32u << 20));        // 8 MiB  (B,H,64,T)
  u16* Ob   = (u16*)(w + (40u << 20));        // 8 MiB  (4096x1024)

  cvt_x_kernel<<<2048, 256, 0, stream>>>(x, xb);
  prep_w_kernel<<<dim3(32, 32, 4), dim3(32, 8), 0, stream>>>(Wq, Wk, Wv, Wo, qw, Wcat, Wot);
  gemm_k<0><<<dim3(24, 32), 256, 0, stream>>>(xb, Wcat, Qb, Kb, Vtb, nullptr);
  attn_k<<<dim3(16, 32), 256, 0, stream>>>(Qb, Kb, Vtb, Ob);
  gemm_k<1><<<dim3(8, 32), 256, 0, stream>>>(Ob, Wot, nullptr, nullptr, nullptr, (float*)d_out);
}

// Round 4
// 163.514 us; speedup vs baseline: 1.3460x; 1.3460x over previous
//
#include <hip/hip_runtime.h>

typedef unsigned short u16;
typedef unsigned int u32;
typedef __attribute__((ext_vector_type(8))) short short8;
typedef __attribute__((ext_vector_type(4))) short short4v;
typedef __attribute__((ext_vector_type(4))) float f32x4;
typedef __attribute__((ext_vector_type(16))) float f32x16;
typedef __attribute__((ext_vector_type(2))) unsigned u32x2;
typedef __attribute__((ext_vector_type(4))) unsigned u32x4;

__device__ __forceinline__ u16 f2bf(float f) {
  union { float f; unsigned u; } a; a.f = f;
  unsigned u = a.u + 0x7fffu + ((a.u >> 16) & 1u);
  return (u16)(u >> 16);
}

__device__ __forceinline__ u32 cvtpk(float lo, float hi_) {
  u32 r; asm("v_cvt_pk_bf16_f32 %0, %1, %2" : "=v"(r) : "v"(lo), "v"(hi_)); return r;
}
__device__ __forceinline__ short8 as_short8(u32x4 v) {
  union { u32x4 u; short8 s; } c; c.u = v; return c.s;
}
__device__ __forceinline__ u32 sh32(u32 v) {  // partner-lane (lane^32) value
  return (u32)__shfl_xor((int)v, 32, 64);
}

// ---------------- x: f32 -> bf16 ----------------
__global__ void cvt_x_kernel(const float* __restrict__ x, u16* __restrict__ xb) {
  int i = (blockIdx.x * 256 + threadIdx.x) * 8;
  float4 a = *(const float4*)(x + i);
  float4 b = *(const float4*)(x + i + 4);
  short8 v;
  v[0] = (short)f2bf(a.x); v[1] = (short)f2bf(a.y);
  v[2] = (short)f2bf(a.z); v[3] = (short)f2bf(a.w);
  v[4] = (short)f2bf(b.x); v[5] = (short)f2bf(b.y);
  v[6] = (short)f2bf(b.z); v[7] = (short)f2bf(b.w);
  *(short8*)(xb + i) = v;
}

// ---------------- weight prep ----------------
__global__ void prep_w_kernel(const float* __restrict__ Wq, const float* __restrict__ Wk,
                              const float* __restrict__ Wv, const float* __restrict__ Wo,
                              const float* __restrict__ qw,
                              u16* __restrict__ Wcat, u16* __restrict__ Wot) {
  __shared__ float tile[32][33];
  const int z = blockIdx.z;
  const int n0 = blockIdx.x * 32, k0 = blockIdx.y * 32;
  const float* src = (z == 0) ? Wq : (z == 1) ? Wk : (z == 2) ? Wv : Wo;
  float w0 = 0.f, w1 = 0.f, w2 = 0.f, w3 = 0.f;
  if (z == 1) {
    float a = qw[0], b = qw[1], c = qw[2], d = qw[3];
    float mx = fmaxf(fmaxf(a, b), fmaxf(c, d));
    float ea = expf(a - mx), eb = expf(b - mx), ec = expf(c - mx), ed = expf(d - mx);
    float s = ea + eb + ec + ed;
    w0 = ea / s; w1 = eb / s; w2 = ec / s; w3 = ed / s;
  }
  #pragma unroll
  for (int i = 0; i < 32; i += 8) {
    int k = k0 + threadIdx.y + i;
    int n = n0 + threadIdx.x;
    float v;
    if (z == 1) {
      int c = n & 63;
      if (c < 32) v = w0 * src[k * 1024 + n]      + w1 * src[k * 1024 + n + 32];
      else        v = w2 * src[k * 1024 + n - 32] + w3 * src[k * 1024 + n];
    } else {
      v = src[k * 1024 + n];
    }
    tile[threadIdx.y + i][threadIdx.x] = v;
  }
  __syncthreads();
  #pragma unroll
  for (int i = 0; i < 32; i += 8) {
    int n = n0 + threadIdx.y + i;
    int k = k0 + threadIdx.x;
    u16 v = f2bf(tile[threadIdx.x][threadIdx.y + i]);
    if (z < 3) Wcat[(size_t)(z * 1024 + n) * 1024 + k] = v;
    else       Wot[(size_t)n * 1024 + k] = v;
  }
}

// ---------------- GEMM: C[M,N] = A[M,K] * B^T[N,K] ----------------
template<int MODE>
__global__ __launch_bounds__(256, 2)
void gemm_k(const u16* __restrict__ A, const u16* __restrict__ Bm,
            u16* __restrict__ out_q, u16* __restrict__ out_k,
            u16* __restrict__ out_vt, float* __restrict__ out_f) {
  __shared__ u16 At[128 * 32];
  __shared__ u16 Bt[128 * 32];
  const int tid = threadIdx.x;
  const int wid = tid >> 6, lane = tid & 63;
  const int l15 = lane & 15, l4 = lane >> 4;
  const int mblk = blockIdx.y * 128, nblk = blockIdx.x * 128;
  const int wm = (wid >> 1) * 64, wn = (wid & 1) * 64;
  f32x4 acc[4][4] = {};

  const int rA = wid * 32 + (lane >> 2);
  const int cA = (lane & 3) * 8;
  const u16* gA = A  + (size_t)(mblk + rA) * 1024 + cA;
  const u16* gB = Bm + (size_t)(nblk + rA) * 1024 + cA;

  for (int kt = 0; kt < 1024; kt += 32) {
    __syncthreads();
    #pragma unroll
    for (int q = 0; q < 2; ++q) {
      __builtin_amdgcn_global_load_lds(
          (__attribute__((address_space(1))) void*)(u16*)(gA + (size_t)q * 16 * 1024 + kt),
          (__attribute__((address_space(3))) void*)(At + (wid * 32 + q * 16) * 32),
          16, 0, 0);
      __builtin_amdgcn_global_load_lds(
          (__attribute__((address_space(1))) void*)(u16*)(gB + (size_t)q * 16 * 1024 + kt),
          (__attribute__((address_space(3))) void*)(Bt + (wid * 32 + q * 16) * 32),
          16, 0, 0);
    }
    __syncthreads();
    short8 af[4], bf[4];
    #pragma unroll
    for (int t = 0; t < 4; ++t) {
      af[t] = *(const short8*)(At + (wm + t * 16 + l15) * 32 + l4 * 8);
      bf[t] = *(const short8*)(Bt + (wn + t * 16 + l15) * 32 + l4 * 8);
    }
    #pragma unroll
    for (int i = 0; i < 4; ++i)
      #pragma unroll
      for (int j = 0; j < 4; ++j)
        acc[i][j] = __builtin_amdgcn_mfma_f32_16x16x32_bf16(af[i], bf[j], acc[i][j], 0, 0, 0);
  }

  #pragma unroll
  for (int i = 0; i < 4; ++i) {
    int m_g = mblk + wm + i * 16 + l4 * 4;
    #pragma unroll
    for (int j = 0; j < 4; ++j) {
      int n_g = nblk + wn + j * 16 + l15;
      f32x4 v = acc[i][j];
      if (MODE == 1) {
        #pragma unroll
        for (int jj = 0; jj < 4; ++jj)
          out_f[(size_t)(m_g + jj) * 1024 + n_g] = v[jj];
      } else {
        if (n_g < 2048) {
          u16* dst = (n_g < 1024) ? out_q : out_k;
          int nn = n_g & 1023;
          #pragma unroll
          for (int jj = 0; jj < 4; ++jj)
            dst[(size_t)(m_g + jj) * 1024 + nn] = f2bf(v[jj]);
        } else {
          int c = n_g - 2048;
          int b = m_g >> 11, t = m_g & 2047;
          short4v p;
          p[0] = (short)f2bf(v[0]); p[1] = (short)f2bf(v[1]);
          p[2] = (short)f2bf(v[2]); p[3] = (short)f2bf(v[3]);
          *(short4v*)(out_vt + ((size_t)((b << 4) + (c >> 6)) * 64 + (c & 63)) * 2048 + t) = p;
        }
      }
    }
  }
}

// ---------------- flash attention, 32x32 swapped-QK^T ----------------
// grid (T/128, B*H); 4 waves x 32 q-rows. KVBLK=64. K/V double-buffered in
// XOR-swizzled LDS (pre-swizzled global src, rule #21).
// QK^T: S^T = mfma(K,Q) -> lane holds P-row of q=lane&31.
// Cross-half exchange via __shfl_xor(...,32) ONLY (no permlane ambiguity).
__global__ __launch_bounds__(256)
void attn_k(const u16* __restrict__ Q, const u16* __restrict__ Kb,
            const u16* __restrict__ Vt, u16* __restrict__ O) {
  __shared__ u16 lk[2][64 * 64];
  __shared__ u16 lv[2][64 * 64];
  const int tid = threadIdx.x, wid = tid >> 6, lane = tid & 63;
  const int l31 = lane & 31, hi = lane >> 5;
  const int qt = blockIdx.x, bh = blockIdx.y;
  const int b = bh >> 4, h = bh & 15;
  const int qrow = qt * 128 + wid * 32 + l31;
  const float c1 = 0.17677669529663687f * 1.4426950408889634f;  // 32^-0.5 * log2(e)

  // Q fragments (B-operand): row=q=l31, k = cs*16 + hi*8 + j.
  short8 qf[4];
  #pragma unroll
  for (int cs = 0; cs < 4; ++cs)
    qf[cs] = *(const short8*)(Q + (size_t)(b * 2048 + qrow) * 1024 + h * 64 + cs * 16 + hi * 8);

  const int sr = lane >> 3;
  const int sc8 = (lane & 7) ^ sr;
  const u16* Kg = Kb + (size_t)b * 2048 * 1024 + h * 64 + sc8 * 8;
  const u16* Vg = Vt + (size_t)bh * 64 * 2048 + sc8 * 8;
  const int s0i = wid * 2;

  f32x16 accO0 = {}, accO1 = {};
  float mrun = -1e30f, lrun = 0.f;

  #pragma unroll
  for (int s2 = 0; s2 < 2; ++s2) {
    int s = s0i + s2;
    int r = s * 8 + sr;
    __builtin_amdgcn_global_load_lds(
      (__attribute__((address_space(1))) void*)(u16*)(Kg + (size_t)r * 1024),
      (__attribute__((address_space(3))) void*)(&lk[0][s * 512]), 16, 0, 0);
    __builtin_amdgcn_global_load_lds(
      (__attribute__((address_space(1))) void*)(u16*)(Vg + (size_t)r * 2048),
      (__attribute__((address_space(3))) void*)(&lv[0][s * 512]), 16, 0, 0);
  }
  __syncthreads();

  int cur = 0;
  const int swz = l31 & 7;

  for (int t = 0; t < 32; ++t) {
    const int kt = t * 64;
    if (t < 31) {
      #pragma unroll
      for (int s2 = 0; s2 < 2; ++s2) {
        int s = s0i + s2;
        int r = s * 8 + sr;
        __builtin_amdgcn_global_load_lds(
          (__attribute__((address_space(1))) void*)(u16*)(Kg + (size_t)(kt + 64 + r) * 1024),
          (__attribute__((address_space(3))) void*)(&lk[cur ^ 1][s * 512]), 16, 0, 0);
        __builtin_amdgcn_global_load_lds(
          (__attribute__((address_space(1))) void*)(u16*)(Vg + (size_t)r * 2048 + kt + 64),
          (__attribute__((address_space(3))) void*)(&lv[cur ^ 1][s * 512]), 16, 0, 0);
      }
    }
    const u16* kb = lk[cur];
    const u16* vb = lv[cur];

    // ---- QK^T ----
    f32x16 s0v = {}, s1v = {};
    #pragma unroll
    for (int cs = 0; cs < 4; ++cs) {
      int ch = cs * 2 + hi;
      short8 k0 = *(const short8*)(kb + l31 * 64 + ((ch ^ swz) * 8));
      short8 k1 = *(const short8*)(kb + (32 + l31) * 64 + ((ch ^ swz) * 8));
      s0v = __builtin_amdgcn_mfma_f32_32x32x16_bf16(k0, qf[cs], s0v, 0, 0, 0);
      s1v = __builtin_amdgcn_mfma_f32_32x32x16_bf16(k1, qf[cs], s1v, 0, 0, 0);
    }
    #pragma unroll
    for (int i = 0; i < 16; ++i) { s0v[i] *= c1; s1v[i] *= c1; }

    // ---- online softmax (q = lane&31); cross-half via shfl_xor 32 ----
    float qa = fmaxf(fmaxf(s0v[0], s0v[1]),  fmaxf(s0v[2], s0v[3]));
    float qb = fmaxf(fmaxf(s0v[4], s0v[5]),  fmaxf(s0v[6], s0v[7]));
    float qc = fmaxf(fmaxf(s0v[8], s0v[9]),  fmaxf(s0v[10], s0v[11]));
    float qd = fmaxf(fmaxf(s0v[12], s0v[13]), fmaxf(s0v[14], s0v[15]));
    float qe = fmaxf(fmaxf(s1v[0], s1v[1]),  fmaxf(s1v[2], s1v[3]));
    float qf2 = fmaxf(fmaxf(s1v[4], s1v[5]), fmaxf(s1v[6], s1v[7]));
    float qg = fmaxf(fmaxf(s1v[8], s1v[9]),  fmaxf(s1v[10], s1v[11]));
    float qh = fmaxf(fmaxf(s1v[12], s1v[13]), fmaxf(s1v[14], s1v[15]));
    float mx = fmaxf(fmaxf(fmaxf(qa, qb), fmaxf(qc, qd)),
                     fmaxf(fmaxf(qe, qf2), fmaxf(qg, qh)));
    mx = fmaxf(mx, __shfl_xor(mx, 32, 64));
    float mnew = fmaxf(mrun, mx);
    float alpha = exp2f(mrun - mnew);
    mrun = mnew;

    #pragma unroll
    for (int i = 0; i < 16; ++i) { s0v[i] = exp2f(s0v[i] - mnew); s1v[i] = exp2f(s1v[i] - mnew); }

    float sa = (s0v[0] + s0v[1]) + (s0v[2] + s0v[3]);
    float sb = (s0v[4] + s0v[5]) + (s0v[6] + s0v[7]);
    float sc_ = (s0v[8] + s0v[9]) + (s0v[10] + s0v[11]);
    float sd = (s0v[12] + s0v[13]) + (s0v[14] + s0v[15]);
    float se = (s1v[0] + s1v[1]) + (s1v[2] + s1v[3]);
    float sf = (s1v[4] + s1v[5]) + (s1v[6] + s1v[7]);
    float sg = (s1v[8] + s1v[9]) + (s1v[10] + s1v[11]);
    float sh = (s1v[12] + s1v[13]) + (s1v[14] + s1v[15]);
    float sm = ((sa + sb) + (sc_ + sd)) + ((se + sf) + (sg + sh));
    sm += __shfl_xor(sm, 32, 64);
    lrun = lrun * alpha + sm;

    #pragma unroll
    for (int i = 0; i < 16; ++i) { accO0[i] *= alpha; accO1[i] *= alpha; }

    // ---- P -> pa fragments via cvtpk + shfl_xor(32) + hi-select ----
    // Targets (B-op k = hi*8+j, keys = ks*16 + k):
    //   w0: hi0 own pk(p0,p1) | hi1 partner pk(p4,p5)
    //   w1: hi0 own pk(p2,p3) | hi1 partner pk(p6,p7)
    //   w2: hi0 partner pk(p0,p1) | hi1 own pk(p4,p5)
    //   w3: hi0 partner pk(p2,p3) | hi1 own pk(p6,p7)
    short8 paS[4];
    #pragma unroll
    for (int half = 0; half < 2; ++half) {
      #pragma unroll
      for (int kq = 0; kq < 2; ++kq) {
        float p0, p1, p2, p3, p4, p5, p6, p7;
        if (half == 0) {
          p0 = s0v[kq*8+0]; p1 = s0v[kq*8+1]; p2 = s0v[kq*8+2]; p3 = s0v[kq*8+3];
          p4 = s0v[kq*8+4]; p5 = s0v[kq*8+5]; p6 = s0v[kq*8+6]; p7 = s0v[kq*8+7];
        } else {
          p0 = s1v[kq*8+0]; p1 = s1v[kq*8+1]; p2 = s1v[kq*8+2]; p3 = s1v[kq*8+3];
          p4 = s1v[kq*8+4]; p5 = s1v[kq*8+5]; p6 = s1v[kq*8+6]; p7 = s1v[kq*8+7];
        }
        u32 A = cvtpk(p0, p1), B = cvtpk(p2, p3);
        u32 C = cvtpk(p4, p5), D = cvtpk(p6, p7);
        u32 sA = sh32(A), sB = sh32(B), sC = sh32(C), sD = sh32(D);
        u32x4 w;
        w[0] = hi ? sC : A;
        w[1] = hi ? sD : B;
        w[2] = hi ? C : sA;
        w[3] = hi ? D : sB;
        paS[half * 2 + kq] = as_short8(w);
      }
    }

    // ---- PV: O^T += V-frag x pa ----
    #pragma unroll
    for (int ks = 0; ks < 4; ++ks) {
      int ch = ks * 2 + hi;
      short8 v0 = *(const short8*)(vb + l31 * 64 + ((ch ^ swz) * 8));
      short8 v1 = *(const short8*)(vb + (32 + l31) * 64 + ((ch ^ swz) * 8));
      accO0 = __builtin_amdgcn_mfma_f32_32x32x16_bf16(v0, paS[ks], accO0, 0, 0, 0);
      accO1 = __builtin_amdgcn_mfma_f32_32x32x16_bf16(v1, paS[ks], accO1, 0, 0, 0);
    }

    __syncthreads();
    cur ^= 1;
  }

  // ---- epilogue: accO[reg] = O^T[d=(reg&3)+8*(reg>>2)+4*hi][q=l31] ----
  float inv = 1.0f / lrun;
  u16* Op = O + (size_t)(b * 2048 + qrow) * 1024 + h * 64;
  #pragma unroll
  for (int g = 0; g < 4; ++g) {
    u32x2 pr;
    pr[0] = cvtpk(accO0[4*g] * inv, accO0[4*g+1] * inv);
    pr[1] = cvtpk(accO0[4*g+2] * inv, accO0[4*g+3] * inv);
    *(u32x2*)(Op + 8*g + 4*hi) = pr;
    u32x2 pr2;
    pr2[0] = cvtpk(accO1[4*g] * inv, accO1[4*g+1] * inv);
    pr2[1] = cvtpk(accO1[4*g+2] * inv, accO1[4*g+3] * inv);
    *(u32x2*)(Op + 32 + 8*g + 4*hi) = pr2;
  }
}

// ---------------- launch ----------------
extern "C" void kernel_launch(void* const* d_in, const int* in_sizes, int n_in,
                              void* d_out, int out_size, void* d_ws, size_t ws_size,
                              hipStream_t stream) {
  const float* x  = (const float*)d_in[0];
  const float* Wq = (const float*)d_in[1];
  const float* Wk = (const float*)d_in[2];
  const float* Wv = (const float*)d_in[3];
  const float* Wo = (const float*)d_in[4];
  const float* qw = (const float*)d_in[5];

  char* w = (char*)d_ws;
  u16* xb   = (u16*)(w);
  u16* Wcat = (u16*)(w + (8u  << 20));
  u16* Wot  = (u16*)(w + (14u << 20));
  u16* Qb   = (u16*)(w + (16u << 20));
  u16* Kb   = (u16*)(w + (24u << 20));
  u16* Vtb  = (u16*)(w + (32u << 20));
  u16* Ob   = (u16*)(w + (40u << 20));

  cvt_x_kernel<<<2048, 256, 0, stream>>>(x, xb);
  prep_w_kernel<<<dim3(32, 32, 4), dim3(32, 8), 0, stream>>>(Wq, Wk, Wv, Wo, qw, Wcat, Wot);
  gemm_k<0><<<dim3(24, 32), 256, 0, stream>>>(xb, Wcat, Qb, Kb, Vtb, nullptr);
  attn_k<<<dim3(16, 32), 256, 0, stream>>>(Qb, Kb, Vtb, Ob);
  gemm_k<1><<<dim3(8, 32), 256, 0, stream>>>(Ob, Wot, nullptr, nullptr, nullptr, (float*)d_out);
}

// Round 5
// 145.638 us; speedup vs baseline: 1.5112x; 1.1227x over previous
//
#include <hip/hip_runtime.h>

typedef unsigned short u16;
typedef unsigned int u32;
typedef __attribute__((ext_vector_type(8))) short short8;
typedef __attribute__((ext_vector_type(4))) short short4v;
typedef __attribute__((ext_vector_type(4))) float f32x4;
typedef __attribute__((ext_vector_type(16))) float f32x16;
typedef __attribute__((ext_vector_type(2))) unsigned u32x2;
typedef __attribute__((ext_vector_type(4))) unsigned u32x4;

__device__ __forceinline__ u16 f2bf(float f) {
  union { float f; unsigned u; } a; a.f = f;
  unsigned u = a.u + 0x7fffu + ((a.u >> 16) & 1u);
  return (u16)(u >> 16);
}

__device__ __forceinline__ u32 cvtpk(float lo, float hi_) {
  u32 r; asm("v_cvt_pk_bf16_f32 %0, %1, %2" : "=v"(r) : "v"(lo), "v"(hi_)); return r;
}
__device__ __forceinline__ short8 as_short8(u32x4 v) {
  union { u32x4 u; short8 s; } c; c.u = v; return c.s;
}
__device__ __forceinline__ u32 sh32(u32 v) {  // partner-lane (lane^32) value
  return (u32)__shfl_xor((int)v, 32, 64);
}
__device__ __forceinline__ float max3f(float a, float b, float c) {
  return fmaxf(fmaxf(a, b), c);  // fuses to v_max3_f32
}

// ---------------- x: f32 -> bf16 ----------------
__global__ void cvt_x_kernel(const float* __restrict__ x, u16* __restrict__ xb) {
  int i = (blockIdx.x * 256 + threadIdx.x) * 8;
  float4 a = *(const float4*)(x + i);
  float4 b = *(const float4*)(x + i + 4);
  short8 v;
  v[0] = (short)f2bf(a.x); v[1] = (short)f2bf(a.y);
  v[2] = (short)f2bf(a.z); v[3] = (short)f2bf(a.w);
  v[4] = (short)f2bf(b.x); v[5] = (short)f2bf(b.y);
  v[6] = (short)f2bf(b.z); v[7] = (short)f2bf(b.w);
  *(short8*)(xb + i) = v;
}

// ---------------- weight prep ----------------
__global__ void prep_w_kernel(const float* __restrict__ Wq, const float* __restrict__ Wk,
                              const float* __restrict__ Wv, const float* __restrict__ Wo,
                              const float* __restrict__ qw,
                              u16* __restrict__ Wcat, u16* __restrict__ Wot) {
  __shared__ float tile[32][33];
  const int z = blockIdx.z;
  const int n0 = blockIdx.x * 32, k0 = blockIdx.y * 32;
  const float* src = (z == 0) ? Wq : (z == 1) ? Wk : (z == 2) ? Wv : Wo;
  float w0 = 0.f, w1 = 0.f, w2 = 0.f, w3 = 0.f;
  if (z == 1) {
    float a = qw[0], b = qw[1], c = qw[2], d = qw[3];
    float mx = fmaxf(fmaxf(a, b), fmaxf(c, d));
    float ea = expf(a - mx), eb = expf(b - mx), ec = expf(c - mx), ed = expf(d - mx);
    float s = ea + eb + ec + ed;
    w0 = ea / s; w1 = eb / s; w2 = ec / s; w3 = ed / s;
  }
  #pragma unroll
  for (int i = 0; i < 32; i += 8) {
    int k = k0 + threadIdx.y + i;
    int n = n0 + threadIdx.x;
    float v;
    if (z == 1) {
      int c = n & 63;
      if (c < 32) v = w0 * src[k * 1024 + n]      + w1 * src[k * 1024 + n + 32];
      else        v = w2 * src[k * 1024 + n - 32] + w3 * src[k * 1024 + n];
    } else {
      v = src[k * 1024 + n];
    }
    tile[threadIdx.y + i][threadIdx.x] = v;
  }
  __syncthreads();
  #pragma unroll
  for (int i = 0; i < 32; i += 8) {
    int n = n0 + threadIdx.y + i;
    int k = k0 + threadIdx.x;
    u16 v = f2bf(tile[threadIdx.x][threadIdx.y + i]);
    if (z < 3) Wcat[(size_t)(z * 1024 + n) * 1024 + k] = v;
    else       Wot[(size_t)n * 1024 + k] = v;
  }
}

// ---------------- GEMM: C[M,N] = A[M,K] * B^T[N,K] ----------------
template<int MODE>
__global__ __launch_bounds__(256, 2)
void gemm_k(const u16* __restrict__ A, const u16* __restrict__ Bm,
            u16* __restrict__ out_q, u16* __restrict__ out_k,
            u16* __restrict__ out_vt, float* __restrict__ out_f) {
  __shared__ u16 At[128 * 32];
  __shared__ u16 Bt[128 * 32];
  const int tid = threadIdx.x;
  const int wid = tid >> 6, lane = tid & 63;
  const int l15 = lane & 15, l4 = lane >> 4;
  const int mblk = blockIdx.y * 128, nblk = blockIdx.x * 128;
  const int wm = (wid >> 1) * 64, wn = (wid & 1) * 64;
  f32x4 acc[4][4] = {};

  const int rA = wid * 32 + (lane >> 2);
  const int cA = (lane & 3) * 8;
  const u16* gA = A  + (size_t)(mblk + rA) * 1024 + cA;
  const u16* gB = Bm + (size_t)(nblk + rA) * 1024 + cA;

  for (int kt = 0; kt < 1024; kt += 32) {
    __syncthreads();
    #pragma unroll
    for (int q = 0; q < 2; ++q) {
      __builtin_amdgcn_global_load_lds(
          (__attribute__((address_space(1))) void*)(u16*)(gA + (size_t)q * 16 * 1024 + kt),
          (__attribute__((address_space(3))) void*)(At + (wid * 32 + q * 16) * 32),
          16, 0, 0);
      __builtin_amdgcn_global_load_lds(
          (__attribute__((address_space(1))) void*)(u16*)(gB + (size_t)q * 16 * 1024 + kt),
          (__attribute__((address_space(3))) void*)(Bt + (wid * 32 + q * 16) * 32),
          16, 0, 0);
    }
    __syncthreads();
    short8 af[4], bf[4];
    #pragma unroll
    for (int t = 0; t < 4; ++t) {
      af[t] = *(const short8*)(At + (wm + t * 16 + l15) * 32 + l4 * 8);
      bf[t] = *(const short8*)(Bt + (wn + t * 16 + l15) * 32 + l4 * 8);
    }
    #pragma unroll
    for (int i = 0; i < 4; ++i)
      #pragma unroll
      for (int j = 0; j < 4; ++j)
        acc[i][j] = __builtin_amdgcn_mfma_f32_16x16x32_bf16(af[i], bf[j], acc[i][j], 0, 0, 0);
  }

  const float QSCALE = 0.17677669529663687f * 1.4426950408889634f; // 32^-0.5 * log2(e)
  #pragma unroll
  for (int i = 0; i < 4; ++i) {
    int m_g = mblk + wm + i * 16 + l4 * 4;
    #pragma unroll
    for (int j = 0; j < 4; ++j) {
      int n_g = nblk + wn + j * 16 + l15;
      f32x4 v = acc[i][j];
      if (MODE == 1) {
        #pragma unroll
        for (int jj = 0; jj < 4; ++jj)
          out_f[(size_t)(m_g + jj) * 1024 + n_g] = v[jj];
      } else {
        if (n_g < 2048) {
          u16* dst; float sc;
          if (n_g < 1024) { dst = out_q; sc = QSCALE; } else { dst = out_k; sc = 1.0f; }
          int nn = n_g & 1023;
          #pragma unroll
          for (int jj = 0; jj < 4; ++jj)
            dst[(size_t)(m_g + jj) * 1024 + nn] = f2bf(v[jj] * sc);
        } else {
          int c = n_g - 2048;
          int b = m_g >> 11, t = m_g & 2047;
          short4v p;
          p[0] = (short)f2bf(v[0]); p[1] = (short)f2bf(v[1]);
          p[2] = (short)f2bf(v[2]); p[3] = (short)f2bf(v[3]);
          *(short4v*)(out_vt + ((size_t)((b << 4) + (c >> 6)) * 64 + (c & 63)) * 2048 + t) = p;
        }
      }
    }
  }
}

// ---------------- flash attention, 32x32 swapped-QK^T ----------------
// Q pre-scaled by 32^-0.5*log2(e). Per tile: max via v_max3 tree + 1 shfl;
// defer-max (THR=8) skips rescale; P row-sum via mfma(ones, paS) into a
// never-zeroed sacc (l = sacc[0] at end); 8 shuffles/tile for P-exchange.
__global__ __launch_bounds__(256)
void attn_k(const u16* __restrict__ Q, const u16* __restrict__ Kb,
            const u16* __restrict__ Vt, u16* __restrict__ O) {
  __shared__ u16 lk[2][64 * 64];
  __shared__ u16 lv[2][64 * 64];
  const int tid = threadIdx.x, wid = tid >> 6, lane = tid & 63;
  const int l31 = lane & 31, hi = lane >> 5;
  const int qt = blockIdx.x, bh = blockIdx.y;
  const int b = bh >> 4, h = bh & 15;
  const int qrow = qt * 128 + wid * 32 + l31;

  // Q fragments (B-operand): row=q=l31, k = cs*16 + hi*8 + j. Pre-scaled.
  short8 qf[4];
  #pragma unroll
  for (int cs = 0; cs < 4; ++cs)
    qf[cs] = *(const short8*)(Q + (size_t)(b * 2048 + qrow) * 1024 + h * 64 + cs * 16 + hi * 8);

  const int sr = lane >> 3;
  const int sc8 = (lane & 7) ^ sr;
  const u16* Kg = Kb + (size_t)b * 2048 * 1024 + h * 64 + sc8 * 8;
  const u16* Vg = Vt + (size_t)bh * 64 * 2048 + sc8 * 8;
  const int s0i = wid * 2;

  // ones A-fragment for row-sum mfma (bf16 1.0 = 0x3F80)
  short8 onesf;
  #pragma unroll
  for (int j = 0; j < 8; ++j) onesf[j] = (short)0x3F80;

  f32x16 accO0 = {}, accO1 = {}, sacc = {};
  float mrun = -1e30f;

  #pragma unroll
  for (int s2 = 0; s2 < 2; ++s2) {
    int s = s0i + s2;
    int r = s * 8 + sr;
    __builtin_amdgcn_global_load_lds(
      (__attribute__((address_space(1))) void*)(u16*)(Kg + (size_t)r * 1024),
      (__attribute__((address_space(3))) void*)(&lk[0][s * 512]), 16, 0, 0);
    __builtin_amdgcn_global_load_lds(
      (__attribute__((address_space(1))) void*)(u16*)(Vg + (size_t)r * 2048),
      (__attribute__((address_space(3))) void*)(&lv[0][s * 512]), 16, 0, 0);
  }
  __syncthreads();

  int cur = 0;
  const int swz = l31 & 7;

  for (int t = 0; t < 32; ++t) {
    const int kt = t * 64;
    if (t < 31) {
      #pragma unroll
      for (int s2 = 0; s2 < 2; ++s2) {
        int s = s0i + s2;
        int r = s * 8 + sr;
        __builtin_amdgcn_global_load_lds(
          (__attribute__((address_space(1))) void*)(u16*)(Kg + (size_t)(kt + 64 + r) * 1024),
          (__attribute__((address_space(3))) void*)(&lk[cur ^ 1][s * 512]), 16, 0, 0);
        __builtin_amdgcn_global_load_lds(
          (__attribute__((address_space(1))) void*)(u16*)(Vg + (size_t)r * 2048 + kt + 64),
          (__attribute__((address_space(3))) void*)(&lv[cur ^ 1][s * 512]), 16, 0, 0);
      }
    }
    const u16* kb = lk[cur];
    const u16* vb = lv[cur];

    // ---- QK^T ----
    f32x16 s0v = {}, s1v = {};
    #pragma unroll
    for (int cs = 0; cs < 4; ++cs) {
      int ch = cs * 2 + hi;
      short8 k0 = *(const short8*)(kb + l31 * 64 + ((ch ^ swz) * 8));
      short8 k1 = *(const short8*)(kb + (32 + l31) * 64 + ((ch ^ swz) * 8));
      s0v = __builtin_amdgcn_mfma_f32_32x32x16_bf16(k0, qf[cs], s0v, 0, 0, 0);
      s1v = __builtin_amdgcn_mfma_f32_32x32x16_bf16(k1, qf[cs], s1v, 0, 0, 0);
    }

    // ---- row max via max3 tree + 1 cross-half shfl ----
    float m01 = max3f(s0v[0], s0v[1], s0v[2]);
    float m02 = max3f(s0v[3], s0v[4], s0v[5]);
    float m03 = max3f(s0v[6], s0v[7], s0v[8]);
    float m04 = max3f(s0v[9], s0v[10], s0v[11]);
    float m05 = max3f(s0v[12], s0v[13], s0v[14]);
    float m11 = max3f(s1v[0], s1v[1], s1v[2]);
    float m12 = max3f(s1v[3], s1v[4], s1v[5]);
    float m13 = max3f(s1v[6], s1v[7], s1v[8]);
    float m14 = max3f(s1v[9], s1v[10], s1v[11]);
    float m15 = max3f(s1v[12], s1v[13], s1v[14]);
    float ma = max3f(m01, m02, m03);
    float mb = max3f(m04, m05, s0v[15]);
    float mc = max3f(m11, m12, m13);
    float md = max3f(m14, m15, s1v[15]);
    float mx = fmaxf(fmaxf(ma, mb), fmaxf(mc, md));
    mx = fmaxf(mx, __shfl_xor(mx, 32, 64));

    // ---- defer-max: rescale only when max grew past THR ----
    if (!__all(mx <= mrun + 8.0f)) {
      float mnew = fmaxf(mrun, mx);
      float al = exp2f(mrun - mnew);
      mrun = mnew;
      sacc[0] *= al;
      #pragma unroll
      for (int i = 0; i < 16; ++i) { accO0[i] *= al; accO1[i] *= al; }
    }

    #pragma unroll
    for (int i = 0; i < 16; ++i) { s0v[i] = exp2f(s0v[i] - mrun); s1v[i] = exp2f(s1v[i] - mrun); }

    // ---- P -> pa fragments (cvtpk + 2 shfl + hi-selects per 8) ----
    short8 paS[4];
    #pragma unroll
    for (int half = 0; half < 2; ++half) {
      #pragma unroll
      for (int kq = 0; kq < 2; ++kq) {
        float p0, p1, p2, p3, p4, p5, p6, p7;
        if (half == 0) {
          p0 = s0v[kq*8+0]; p1 = s0v[kq*8+1]; p2 = s0v[kq*8+2]; p3 = s0v[kq*8+3];
          p4 = s0v[kq*8+4]; p5 = s0v[kq*8+5]; p6 = s0v[kq*8+6]; p7 = s0v[kq*8+7];
        } else {
          p0 = s1v[kq*8+0]; p1 = s1v[kq*8+1]; p2 = s1v[kq*8+2]; p3 = s1v[kq*8+3];
          p4 = s1v[kq*8+4]; p5 = s1v[kq*8+5]; p6 = s1v[kq*8+6]; p7 = s1v[kq*8+7];
        }
        u32 A = cvtpk(p0, p1), B = cvtpk(p2, p3);
        u32 C = cvtpk(p4, p5), D = cvtpk(p6, p7);
        u32 e1 = sh32(hi ? A : C);   // hi=0 gets partner's A; hi=1 gets partner's C
        u32 e2 = sh32(hi ? B : D);
        u32x4 w;
        w[0] = hi ? e1 : A;
        w[1] = hi ? e2 : B;
        w[2] = hi ? C : e1;
        w[3] = hi ? D : e2;
        paS[half * 2 + kq] = as_short8(w);
      }
    }

    // ---- PV: O^T += V-frag x pa ;  row-sum: sacc += ones x pa ----
    #pragma unroll
    for (int ks = 0; ks < 4; ++ks) {
      int ch = ks * 2 + hi;
      short8 v0 = *(const short8*)(vb + l31 * 64 + ((ch ^ swz) * 8));
      short8 v1 = *(const short8*)(vb + (32 + l31) * 64 + ((ch ^ swz) * 8));
      accO0 = __builtin_amdgcn_mfma_f32_32x32x16_bf16(v0, paS[ks], accO0, 0, 0, 0);
      accO1 = __builtin_amdgcn_mfma_f32_32x32x16_bf16(v1, paS[ks], accO1, 0, 0, 0);
      sacc  = __builtin_amdgcn_mfma_f32_32x32x16_bf16(onesf, paS[ks], sacc, 0, 0, 0);
    }

    __syncthreads();
    cur ^= 1;
  }

  // ---- epilogue: accO[reg] = O^T[d=(reg&3)+8*(reg>>2)+4*hi][q=l31]; l = sacc[0] ----
  float inv = 1.0f / sacc[0];
  u16* Op = O + (size_t)(b * 2048 + qrow) * 1024 + h * 64;
  #pragma unroll
  for (int g = 0; g < 4; ++g) {
    u32x2 pr;
    pr[0] = cvtpk(accO0[4*g] * inv, accO0[4*g+1] * inv);
    pr[1] = cvtpk(accO0[4*g+2] * inv, accO0[4*g+3] * inv);
    *(u32x2*)(Op + 8*g + 4*hi) = pr;
    u32x2 pr2;
    pr2[0] = cvtpk(accO1[4*g] * inv, accO1[4*g+1] * inv);
    pr2[1] = cvtpk(accO1[4*g+2] * inv, accO1[4*g+3] * inv);
    *(u32x2*)(Op + 32 + 8*g + 4*hi) = pr2;
  }
}

// ---------------- launch ----------------
extern "C" void kernel_launch(void* const* d_in, const int* in_sizes, int n_in,
                              void* d_out, int out_size, void* d_ws, size_t ws_size,
                              hipStream_t stream) {
  const float* x  = (const float*)d_in[0];
  const float* Wq = (const float*)d_in[1];
  const float* Wk = (const float*)d_in[2];
  const float* Wv = (const float*)d_in[3];
  const float* Wo = (const float*)d_in[4];
  const float* qw = (const float*)d_in[5];

  char* w = (char*)d_ws;
  u16* xb   = (u16*)(w);
  u16* Wcat = (u16*)(w + (8u  << 20));
  u16* Wot  = (u16*)(w + (14u << 20));
  u16* Qb   = (u16*)(w + (16u << 20));
  u16* Kb   = (u16*)(w + (24u << 20));
  u16* Vtb  = (u16*)(w + (32u << 20));
  u16* Ob   = (u16*)(w + (40u << 20));

  cvt_x_kernel<<<2048, 256, 0, stream>>>(x, xb);
  prep_w_kernel<<<dim3(32, 32, 4), dim3(32, 8), 0, stream>>>(Wq, Wk, Wv, Wo, qw, Wcat, Wot);
  gemm_k<0><<<dim3(24, 32), 256, 0, stream>>>(xb, Wcat, Qb, Kb, Vtb, nullptr);
  attn_k<<<dim3(16, 32), 256, 0, stream>>>(Qb, Kb, Vtb, Ob);
  gemm_k<1><<<dim3(8, 32), 256, 0, stream>>>(Ob, Wot, nullptr, nullptr, nullptr, (float*)d_out);
}